// Round 1
// baseline (1466.724 us; speedup 1.0000x reference)
//
#include <hip/hip_runtime.h>
#include <hip/hip_bf16.h>
#include <stdint.h>

#define T_SEQ  2048
#define HIDDEN 4096
#define NHEAD  32
#define NKV    8
#define HDIM   128
#define NQKV   6144      // (32 + 2*8) * 128
#define WINDOW 1024

typedef __attribute__((ext_vector_type(8))) short   short8;   // 8 bf16 = 4 VGPRs
typedef __attribute__((ext_vector_type(4))) float   floatx4;

__device__ __forceinline__ unsigned short f2bf(float f) {
    union { float f; unsigned int u; } v; v.f = f;
    unsigned int u = v.u;
    unsigned int r = (u + 0x7FFFu + ((u >> 16) & 1u)) >> 16;  // RNE
    return (unsigned short)r;
}

// ---------------------------------------------------------------- convert fp32 -> bf16
__global__ __launch_bounds__(256) void convert_bf16_kernel(
        const float* __restrict__ X, unsigned short* __restrict__ Y, int n4) {
    int i = blockIdx.x * blockDim.x + threadIdx.x;
    if (i < n4) {
        float4 v = ((const float4*)X)[i];
        ushort4 o;
        o.x = f2bf(v.x); o.y = f2bf(v.y); o.z = f2bf(v.z); o.w = f2bf(v.w);
        ((ushort4*)Y)[i] = o;
    }
}

// ------------------------------------------- transpose K x N fp32 -> N x K bf16
__global__ void transpose_bf16_kernel(const float* __restrict__ W,
                                      unsigned short* __restrict__ Wt,
                                      int K, int N) {
    __shared__ float tile[32][33];
    int n0 = blockIdx.x * 32, k0 = blockIdx.y * 32;
    int tx = threadIdx.x, ty = threadIdx.y;   // 32 x 8
    #pragma unroll
    for (int i = 0; i < 4; ++i)
        tile[ty + i*8][tx] = W[(size_t)(k0 + ty + i*8) * N + n0 + tx];
    __syncthreads();
    #pragma unroll
    for (int i = 0; i < 4; ++i)
        Wt[(size_t)(n0 + ty + i*8) * K + k0 + tx] = f2bf(tile[tx][ty + i*8]);
}

// ---------------------------------------------------------------- bf16 MFMA GEMM
// A: M x K bf16 row-major.  B: N x K bf16 row-major (i.e. B^T of the K x N weight).
// C: M x N fp32 row-major.  Tile 128x128, BK=32, 4 waves (2x2), 16x16x32 MFMA.
#define GLOBAL_AS(p) ((const __attribute__((address_space(1))) void*)(p))
#define LDS_AS(p)    ((__attribute__((address_space(3))) void*)(p))

__global__ __launch_bounds__(256) void gemm_bt_kernel(
        const unsigned short* __restrict__ A,
        const unsigned short* __restrict__ B,
        float* __restrict__ C, int M, int N, int K) {
    __shared__ __align__(16) unsigned short As[128 * 32];
    __shared__ __align__(16) unsigned short Bs[128 * 32];
    const int tid  = threadIdx.x;
    const int lane = tid & 63, wave = tid >> 6;
    const int wr = wave >> 1, wc = wave & 1;
    const int m0 = blockIdx.y * 128, n0 = blockIdx.x * 128;

    floatx4 acc[4][4] = {};

    const int lrow = lane & 15;
    const int lk   = (lane >> 4) * 8;

    for (int k0 = 0; k0 < K; k0 += 32) {
        // stage A,B tiles: 512 chunks of 16B each, 256 lanes x 2 issues.
        // chunk c: row = c>>2 (LDS row stride 32 elems = 64B), col-chunk = c&3.
        // LDS dest = base + c*16B == wave-uniform base + lane*16 (global_load_lds rule).
        #pragma unroll
        for (int i = 0; i < 2; ++i) {
            int c = i * 256 + tid;
            const unsigned short* gpA = A + (size_t)(m0 + (c >> 2)) * K + k0 + (c & 3) * 8;
            __builtin_amdgcn_global_load_lds(GLOBAL_AS(gpA), LDS_AS(As + c * 8), 16, 0, 0);
            const unsigned short* gpB = B + (size_t)(n0 + (c >> 2)) * K + k0 + (c & 3) * 8;
            __builtin_amdgcn_global_load_lds(GLOBAL_AS(gpB), LDS_AS(Bs + c * 8), 16, 0, 0);
        }
        __syncthreads();

        short8 af[4], bf[4];
        #pragma unroll
        for (int t = 0; t < 4; ++t) {
            af[t] = *(const short8*)(As + (wr * 64 + t * 16 + lrow) * 32 + lk);
            bf[t] = *(const short8*)(Bs + (wc * 64 + t * 16 + lrow) * 32 + lk);
        }
        #pragma unroll
        for (int ti = 0; ti < 4; ++ti)
            #pragma unroll
            for (int tj = 0; tj < 4; ++tj)
                acc[ti][tj] = __builtin_amdgcn_mfma_f32_16x16x32_bf16(
                    af[ti], bf[tj], acc[ti][tj], 0, 0, 0);
        __syncthreads();
    }

    // C/D layout: lane holds D[m=(lane>>4)*4 + r][n=lane&15]
    const int rowb = (lane >> 4) * 4, col = lane & 15;
    #pragma unroll
    for (int ti = 0; ti < 4; ++ti)
        #pragma unroll
        for (int tj = 0; tj < 4; ++tj) {
            size_t base = (size_t)(m0 + wr * 64 + ti * 16 + rowb) * N
                        + (n0 + wc * 64 + tj * 16 + col);
            #pragma unroll
            for (int r = 0; r < 4; ++r)
                C[base + (size_t)r * N] = acc[ti][tj][r];
        }
}

// ------------------------------------------- RMSNorm + NeoX RoPE on q,k (in place)
__global__ __launch_bounds__(128) void norm_rope_kernel(
        float* __restrict__ qkv, const int* __restrict__ positions,
        const float* __restrict__ qw, const float* __restrict__ kw) {
    const int b = blockIdx.x;
    const int t = b / 40, head = b % 40;    // 32 q heads + 8 k heads
    float* row;
    const float* w;
    if (head < 32) { row = qkv + (size_t)t * NQKV + head * 128;               w = qw; }
    else           { row = qkv + (size_t)t * NQKV + 4096 + (head - 32) * 128; w = kw; }
    const int tid = threadIdx.x;   // 128
    float x = row[tid];
    float ss = x * x;
    #pragma unroll
    for (int off = 32; off > 0; off >>= 1) ss += __shfl_down(ss, off);
    __shared__ float partial[2];
    __shared__ float nbuf[128];
    if ((tid & 63) == 0) partial[tid >> 6] = ss;
    __syncthreads();
    float tot   = partial[0] + partial[1];
    float scale = rsqrtf(tot * (1.f / 128.f) + 1e-5f);
    nbuf[tid] = x * scale * w[tid];
    __syncthreads();
    int i = tid & 63;
    float inv_freq = expf((float)i * -0.2158673524681918f);   // -ln(1e6)/64
    float ang = (float)positions[t] * inv_freq;
    float sn, cs;
    sincosf(ang, &sn, &cs);
    float x1 = nbuf[i], x2 = nbuf[i + 64];
    row[tid] = (tid < 64) ? (x1 * cs - x2 * sn) : (x2 * cs + x1 * sn);
}

// ------------------------------------------- sliding-window flash attention (fp32)
// Block = one head x 64 queries (4 waves x 16 queries). Lane = (qi = lane>>2, dq = lane&3):
// each lane owns a 32-element d-slice of one query. k/v staged in LDS 16 keys at a time.
__global__ __launch_bounds__(256) void attention_kernel(
        const float* __restrict__ qkv, unsigned short* __restrict__ attnb) {
    const int h   = blockIdx.x & 31;
    const int Q0  = (blockIdx.x >> 5) * 64;
    const int tid = threadIdx.x, wave = tid >> 6, lane = tid & 63;
    const int qi = lane >> 2, dq = lane & 3;
    const int qg = Q0 + wave * 16 + qi;
    const int hk = h >> 2;
    __shared__ float ks[16][128];
    __shared__ float vs[16][128];

    float qreg[32], o[32];
    const float* qrow = qkv + (size_t)qg * NQKV + h * 128 + dq * 32;
    const float scale = 0.08838834764831845f;   // 1/sqrt(128)
    #pragma unroll
    for (int e = 0; e < 32; ++e) { qreg[e] = qrow[e] * scale; o[e] = 0.f; }
    float mrun = -INFINITY, lrun = 0.f;

    int s_begin = Q0 - (WINDOW - 1); if (s_begin < 0) s_begin = 0;
    const int s_end = Q0 + 63;
    const int qlo   = Q0 + wave * 16;

    for (int s0 = s_begin; s0 <= s_end; s0 += 16) {
        {   // cooperative load: 16 keys x 128 floats for k and v
            const int r = tid >> 4, cOff = (tid & 15) * 8;
            const int s = s0 + r;
            if (s < T_SEQ) {
                const float* kp = qkv + (size_t)s * NQKV + 4096 + hk * 128 + cOff;
                const float* vp = kp + 1024;   // v starts 1024 floats after k start
                *(float4*)&ks[r][cOff]     = *(const float4*)kp;
                *(float4*)&ks[r][cOff + 4] = *(const float4*)(kp + 4);
                *(float4*)&vs[r][cOff]     = *(const float4*)vp;
                *(float4*)&vs[r][cOff + 4] = *(const float4*)(vp + 4);
            }
        }
        __syncthreads();
        bool active = (s0 <= qlo + 15) && (s0 + 15 >= qlo - (WINDOW - 1));
        if (active) {
            float sc[16];
            #pragma unroll
            for (int j = 0; j < 16; ++j) {
                const int s = s0 + j;
                float p = 0.f;
                #pragma unroll
                for (int e = 0; e < 32; ++e) p = fmaf(qreg[e], ks[j][dq * 32 + e], p);
                p += __shfl_xor(p, 1);
                p += __shfl_xor(p, 2);   // all 4 dq lanes now hold the full dot
                bool valid = (s <= qg) && (qg - s < WINDOW) && (s < T_SEQ);
                sc[j] = valid ? p : -INFINITY;
            }
            float cmax = -INFINITY;
            #pragma unroll
            for (int j = 0; j < 16; ++j) cmax = fmaxf(cmax, sc[j]);
            if (cmax > -1e30f) {
                float mnew  = fmaxf(mrun, cmax);
                float alpha = __expf(mrun - mnew);   // exp(-inf)=0 handles first chunk
                lrun *= alpha;
                #pragma unroll
                for (int e = 0; e < 32; ++e) o[e] *= alpha;
                #pragma unroll
                for (int j = 0; j < 16; ++j) {
                    float pj = __expf(sc[j] - mnew);
                    lrun += pj;
                    #pragma unroll
                    for (int e = 0; e < 32; ++e) o[e] = fmaf(pj, vs[j][dq * 32 + e], o[e]);
                }
                mrun = mnew;
            }
        }
        __syncthreads();
    }
    const float inv = 1.f / lrun;
    unsigned short* op = attnb + (size_t)qg * 4096 + h * 128 + dq * 32;
    #pragma unroll
    for (int e = 0; e < 32; ++e) op[e] = f2bf(o[e] * inv);
}

// ----------------------------------------------------------------------- launcher
extern "C" void kernel_launch(void* const* d_in, const int* in_sizes, int n_in,
                              void* d_out, int out_size, void* d_ws, size_t ws_size,
                              hipStream_t stream) {
    const int*   positions = (const int*)  d_in[0];
    const float* hs        = (const float*)d_in[1];
    const float* w_qkv     = (const float*)d_in[2];
    const float* q_norm_w  = (const float*)d_in[3];
    const float* k_norm_w  = (const float*)d_in[4];
    const float* w_o       = (const float*)d_in[5];
    float* out = (float*)d_out;

    char* ws = (char*)d_ws;
    // layout (144 MB total):
    //   [0,16M)    hs bf16          (dead after gemm1; reused as attn bf16)
    //   [16M,64M)  w_qkv^T bf16
    //   [64M,96M)  w_o^T bf16
    //   [96M,144M) qkv fp32
    unsigned short* hsb   = (unsigned short*)(ws);
    unsigned short* wqkvt = (unsigned short*)(ws + (size_t)(16u << 20));
    unsigned short* wot   = (unsigned short*)(ws + (size_t)(64u << 20));
    float*          qkv   = (float*)         (ws + (size_t)(96u << 20));
    unsigned short* attnb = hsb;   // alias: hs-bf16 no longer needed by then

    convert_bf16_kernel<<<dim3((T_SEQ * HIDDEN / 4 + 255) / 256), 256, 0, stream>>>(
        hs, hsb, T_SEQ * HIDDEN / 4);
    transpose_bf16_kernel<<<dim3(NQKV / 32, HIDDEN / 32), dim3(32, 8), 0, stream>>>(
        w_qkv, wqkvt, HIDDEN, NQKV);
    transpose_bf16_kernel<<<dim3(HIDDEN / 32, HIDDEN / 32), dim3(32, 8), 0, stream>>>(
        w_o, wot, HIDDEN, HIDDEN);
    gemm_bt_kernel<<<dim3(NQKV / 128, T_SEQ / 128), 256, 0, stream>>>(
        hsb, wqkvt, qkv, T_SEQ, NQKV, HIDDEN);
    norm_rope_kernel<<<dim3(T_SEQ * 40), 128, 0, stream>>>(
        qkv, positions, q_norm_w, k_norm_w);
    attention_kernel<<<dim3((T_SEQ / 64) * NHEAD), 256, 0, stream>>>(qkv, attnb);
    gemm_bt_kernel<<<dim3(HIDDEN / 128, T_SEQ / 128), 256, 0, stream>>>(
        attnb, wot, out, T_SEQ, HIDDEN, HIDDEN);
}

// Round 2
// 631.376 us; speedup vs baseline: 2.3231x; 2.3231x over previous
//
#include <hip/hip_runtime.h>
#include <hip/hip_bf16.h>
#include <stdint.h>

#define T_SEQ  2048
#define HIDDEN 4096
#define NHEAD  32
#define NKV    8
#define HDIM   128
#define NQKV   6144      // (32 + 2*8) * 128
#define WINDOW 1024
#define SCALE  0.08838834764831845f   // 1/sqrt(128)

typedef __attribute__((ext_vector_type(8))) short   short8;   // 8 bf16 = 4 VGPRs
typedef __attribute__((ext_vector_type(4))) float   floatx4;

__device__ __forceinline__ unsigned short f2bf(float f) {
    union { float f; unsigned int u; } v; v.f = f;
    unsigned int u = v.u;
    unsigned int r = (u + 0x7FFFu + ((u >> 16) & 1u)) >> 16;  // RNE
    return (unsigned short)r;
}

// ---------------------------------------------------------------- convert fp32 -> bf16
__global__ __launch_bounds__(256) void convert_bf16_kernel(
        const float* __restrict__ X, unsigned short* __restrict__ Y, int n4) {
    int i = blockIdx.x * blockDim.x + threadIdx.x;
    if (i < n4) {
        float4 v = ((const float4*)X)[i];
        ushort4 o;
        o.x = f2bf(v.x); o.y = f2bf(v.y); o.z = f2bf(v.z); o.w = f2bf(v.w);
        ((ushort4*)Y)[i] = o;
    }
}

// ------------------------------------------- transpose K x N fp32 -> N x K bf16
__global__ void transpose_bf16_kernel(const float* __restrict__ W,
                                      unsigned short* __restrict__ Wt,
                                      int K, int N) {
    __shared__ float tile[32][33];
    int n0 = blockIdx.x * 32, k0 = blockIdx.y * 32;
    int tx = threadIdx.x, ty = threadIdx.y;   // 32 x 8
    #pragma unroll
    for (int i = 0; i < 4; ++i)
        tile[ty + i*8][tx] = W[(size_t)(k0 + ty + i*8) * N + n0 + tx];
    __syncthreads();
    #pragma unroll
    for (int i = 0; i < 4; ++i)
        Wt[(size_t)(n0 + ty + i*8) * K + k0 + tx] = f2bf(tile[tx][ty + i*8]);
}

// ------------------------------------------- transpose V: qkv fp32 [T][6144] -> vbT bf16 [8][128][T]
__global__ void vtrans_kernel(const float* __restrict__ qkv,
                              unsigned short* __restrict__ vbT) {
    __shared__ float tile[32][33];
    int s0 = blockIdx.x * 32, d0 = blockIdx.y * 32, hk = blockIdx.z;
    int tx = threadIdx.x, ty = threadIdx.y;   // 32 x 8
    #pragma unroll
    for (int i = 0; i < 4; ++i)
        tile[ty + i*8][tx] = qkv[(size_t)(s0 + ty + i*8) * NQKV + 5120 + hk * 128 + d0 + tx];
    __syncthreads();
    #pragma unroll
    for (int i = 0; i < 4; ++i)
        vbT[((size_t)hk * 128 + d0 + ty + i*8) * T_SEQ + s0 + tx] = f2bf(tile[tx][ty + i*8]);
}

// ---------------------------------------------------------------- bf16 MFMA GEMM
#define GLOBAL_AS(p) ((const __attribute__((address_space(1))) void*)(p))
#define LDS_AS(p)    ((__attribute__((address_space(3))) void*)(p))

__global__ __launch_bounds__(256) void gemm_bt_kernel(
        const unsigned short* __restrict__ A,
        const unsigned short* __restrict__ B,
        float* __restrict__ C, int M, int N, int K) {
    __shared__ __align__(16) unsigned short As[128 * 32];
    __shared__ __align__(16) unsigned short Bs[128 * 32];
    const int tid  = threadIdx.x;
    const int lane = tid & 63, wave = tid >> 6;
    const int wr = wave >> 1, wc = wave & 1;
    const int m0 = blockIdx.y * 128, n0 = blockIdx.x * 128;

    floatx4 acc[4][4] = {};

    const int lrow = lane & 15;
    const int lk   = (lane >> 4) * 8;

    for (int k0 = 0; k0 < K; k0 += 32) {
        #pragma unroll
        for (int i = 0; i < 2; ++i) {
            int c = i * 256 + tid;
            const unsigned short* gpA = A + (size_t)(m0 + (c >> 2)) * K + k0 + (c & 3) * 8;
            __builtin_amdgcn_global_load_lds(GLOBAL_AS(gpA), LDS_AS(As + c * 8), 16, 0, 0);
            const unsigned short* gpB = B + (size_t)(n0 + (c >> 2)) * K + k0 + (c & 3) * 8;
            __builtin_amdgcn_global_load_lds(GLOBAL_AS(gpB), LDS_AS(Bs + c * 8), 16, 0, 0);
        }
        __syncthreads();

        short8 af[4], bf[4];
        #pragma unroll
        for (int t = 0; t < 4; ++t) {
            af[t] = *(const short8*)(As + (wr * 64 + t * 16 + lrow) * 32 + lk);
            bf[t] = *(const short8*)(Bs + (wc * 64 + t * 16 + lrow) * 32 + lk);
        }
        #pragma unroll
        for (int ti = 0; ti < 4; ++ti)
            #pragma unroll
            for (int tj = 0; tj < 4; ++tj)
                acc[ti][tj] = __builtin_amdgcn_mfma_f32_16x16x32_bf16(
                    af[ti], bf[tj], acc[ti][tj], 0, 0, 0);
        __syncthreads();
    }

    const int rowb = (lane >> 4) * 4, col = lane & 15;
    #pragma unroll
    for (int ti = 0; ti < 4; ++ti)
        #pragma unroll
        for (int tj = 0; tj < 4; ++tj) {
            size_t base = (size_t)(m0 + wr * 64 + ti * 16 + rowb) * N
                        + (n0 + wc * 64 + tj * 16 + col);
            #pragma unroll
            for (int r = 0; r < 4; ++r)
                C[base + (size_t)r * N] = acc[ti][tj][r];
        }
}

// ------------------------------------------- RMSNorm + NeoX RoPE on q,k -> bf16 qb/kb
__global__ __launch_bounds__(128) void norm_rope_kernel(
        const float* __restrict__ qkv, const int* __restrict__ positions,
        const float* __restrict__ qw, const float* __restrict__ kw,
        unsigned short* __restrict__ qb, unsigned short* __restrict__ kb) {
    const int b = blockIdx.x;
    const int t = b / 40, head = b % 40;    // 32 q heads + 8 k heads
    const float* row;
    const float* w;
    unsigned short* dst;
    if (head < 32) { row = qkv + (size_t)t * NQKV + head * 128;               w = qw;
                     dst = qb + ((size_t)t * 32 + head) * 128; }
    else           { row = qkv + (size_t)t * NQKV + 4096 + (head - 32) * 128; w = kw;
                     dst = kb + ((size_t)t * 8 + (head - 32)) * 128; }
    const int tid = threadIdx.x;   // 128
    float x = row[tid];
    float ss = x * x;
    #pragma unroll
    for (int off = 32; off > 0; off >>= 1) ss += __shfl_down(ss, off);
    __shared__ float partial[2];
    __shared__ float nbuf[128];
    if ((tid & 63) == 0) partial[tid >> 6] = ss;
    __syncthreads();
    float tot   = partial[0] + partial[1];
    float scale = rsqrtf(tot * (1.f / 128.f) + 1e-5f);
    nbuf[tid] = x * scale * w[tid];
    __syncthreads();
    int i = tid & 63;
    float inv_freq = expf((float)i * -0.2158673524681918f);   // -ln(1e6)/64
    float ang = (float)positions[t] * inv_freq;
    float sn, cs;
    sincosf(ang, &sn, &cs);
    float x1 = nbuf[i], x2 = nbuf[i + 64];
    float res = (tid < 64) ? (x1 * cs - x2 * sn) : (x2 * cs + x1 * sn);
    dst[tid] = f2bf(res);
}

// ------------------------------------------- MFMA sliding-window flash attention
// Block = one q-head x 64 queries, 4 waves; wave owns 16 queries. Chunk = 32 keys.
// QK^T: 8x mfma_16x16x32_bf16; online softmax in C-layout regs; P->LDS->A-frag;
// PV: 8x mfma into O (16x128) C-layout accumulator.
__global__ __launch_bounds__(256) void attention_kernel(
        const unsigned short* __restrict__ qb,
        const unsigned short* __restrict__ kb,
        const unsigned short* __restrict__ vbT,
        unsigned short* __restrict__ attnb) {
    const int h    = blockIdx.x & 31;
    const int Q0   = (blockIdx.x >> 5) * 64;
    const int tid  = threadIdx.x, wave = tid >> 6, lane = tid & 63;
    const int keyA = lane & 15, g = lane >> 4;
    const int hk   = h >> 2;
    const int qlo  = Q0 + wave * 16;

    // unpadded (global_load_lds needs contiguity); reads de-conflicted by XOR
    // swizzle of the 16B-chunk index applied on the GLOBAL source side.
    __shared__ __align__(16) unsigned short ks [32 * 128];   // [key][d]
    __shared__ __align__(16) unsigned short vsT[128 * 32];   // [d][key]
    __shared__ __align__(16) unsigned short Pa [4 * 16 * 40];// per-wave 16x32 (+8 pad)

    unsigned short* pw = Pa + wave * 640;

    // Q A-frags: lane holds Q[m=keyA][k=g*8+j+32*kst]
    short8 qa[4];
    {
        const unsigned short* qp = qb + ((size_t)(qlo + keyA) * 32 + h) * 128 + g * 8;
        #pragma unroll
        for (int s = 0; s < 4; ++s) qa[s] = *(const short8*)(qp + s * 32);
    }

    floatx4 acc[8] = {};                 // O: rows 4g+r, cols dtile*16+keyA
    float m_run[4], l_run[4];
    #pragma unroll
    for (int r = 0; r < 4; ++r) { m_run[r] = -INFINITY; l_run[r] = 0.f; }

    const int s_begin = (Q0 >= WINDOW) ? ((Q0 - (WINDOW - 1)) & ~31) : 0;
    const int s_end   = Q0 + 63;

    for (int s0 = s_begin; s0 <= s_end; s0 += 32) {
        // ---- stage K (32x128) and V^T (128x32) bf16 via global_load_lds w=16
        #pragma unroll
        for (int i = 0; i < 2; ++i) {
            int c = i * 256 + tid;
            {   int row = c >> 4, u = c & 15, su = u ^ (row & 7);
                const unsigned short* kp = kb + ((size_t)(s0 + row) * 8 + hk) * 128 + su * 8;
                __builtin_amdgcn_global_load_lds(GLOBAL_AS(kp), LDS_AS(ks + c * 8), 16, 0, 0); }
            {   int d = c >> 2, u = c & 3, su = u ^ (d & 3);
                const unsigned short* vp = vbT + ((size_t)hk * 128 + d) * T_SEQ + s0 + su * 8;
                __builtin_amdgcn_global_load_lds(GLOBAL_AS(vp), LDS_AS(vsT + c * 8), 16, 0, 0); }
        }
        __syncthreads();

        if (s0 <= qlo + 15 && s0 + 31 >= qlo - (WINDOW - 1)) {
            // ---- QK^T: two 16x16 score tiles over K=128
            floatx4 sa0 = {}, sa1 = {};
            #pragma unroll
            for (int kst = 0; kst < 4; ++kst) {
                int u = g + 4 * kst;
                short8 k0 = *(const short8*)(ks + keyA * 128 + (u ^ (keyA & 7)) * 8);
                short8 k1 = *(const short8*)(ks + (16 + keyA) * 128 + (u ^ ((16 + keyA) & 7)) * 8);
                sa0 = __builtin_amdgcn_mfma_f32_16x16x32_bf16(qa[kst], k0, sa0, 0, 0, 0);
                sa1 = __builtin_amdgcn_mfma_f32_16x16x32_bf16(qa[kst], k1, sa1, 0, 0, 0);
            }
            // ---- online softmax (rows 4g+r; cols keyA / keyA+16)
            float p0[4], p1[4], alpha[4];
            #pragma unroll
            for (int r = 0; r < 4; ++r) {
                int row = qlo + 4 * g + r;
                int sA = s0 + keyA, sB = sA + 16;
                float v0 = (sA <= row && row - sA < WINDOW) ? sa0[r] * SCALE : -INFINITY;
                float v1 = (sB <= row && row - sB < WINDOW) ? sa1[r] * SCALE : -INFINITY;
                float mx = fmaxf(v0, v1);
                mx = fmaxf(mx, __shfl_xor(mx, 1));
                mx = fmaxf(mx, __shfl_xor(mx, 2));
                mx = fmaxf(mx, __shfl_xor(mx, 4));
                mx = fmaxf(mx, __shfl_xor(mx, 8));
                float mnew  = fmaxf(m_run[r], mx);
                float msafe = fmaxf(mnew, -1e30f);   // all-masked row guard
                alpha[r] = __expf(m_run[r] - msafe);
                p0[r] = __expf(v0 - msafe);
                p1[r] = __expf(v1 - msafe);
                float sum = p0[r] + p1[r];
                sum += __shfl_xor(sum, 1);
                sum += __shfl_xor(sum, 2);
                sum += __shfl_xor(sum, 4);
                sum += __shfl_xor(sum, 8);
                l_run[r] = l_run[r] * alpha[r] + sum;
                m_run[r] = mnew;
            }
            #pragma unroll
            for (int t = 0; t < 8; ++t)
                #pragma unroll
                for (int r = 0; r < 4; ++r) acc[t][r] *= alpha[r];

            // ---- P (C-layout) -> LDS -> A-frag (per-wave region, no barrier)
            #pragma unroll
            for (int r = 0; r < 4; ++r) {
                pw[(4 * g + r) * 40 + keyA]      = f2bf(p0[r]);
                pw[(4 * g + r) * 40 + keyA + 16] = f2bf(p1[r]);
            }
            short8 pf = *(const short8*)(pw + keyA * 40 + g * 8);

            // ---- PV: O += P(16x32) . V(32x128)
            #pragma unroll
            for (int t = 0; t < 8; ++t) {
                int d = t * 16 + keyA;
                short8 vf = *(const short8*)(vsT + d * 32 + (g ^ (d & 3)) * 8);
                acc[t] = __builtin_amdgcn_mfma_f32_16x16x32_bf16(pf, vf, acc[t], 0, 0, 0);
            }
        }
        __syncthreads();
    }

    float inv[4];
    #pragma unroll
    for (int r = 0; r < 4; ++r) inv[r] = 1.f / l_run[r];
    #pragma unroll
    for (int t = 0; t < 8; ++t)
        #pragma unroll
        for (int r = 0; r < 4; ++r)
            attnb[(size_t)(qlo + 4 * g + r) * 4096 + h * 128 + t * 16 + keyA] =
                f2bf(acc[t][r] * inv[r]);
}

// ----------------------------------------------------------------------- launcher
extern "C" void kernel_launch(void* const* d_in, const int* in_sizes, int n_in,
                              void* d_out, int out_size, void* d_ws, size_t ws_size,
                              hipStream_t stream) {
    const int*   positions = (const int*)  d_in[0];
    const float* hs        = (const float*)d_in[1];
    const float* w_qkv     = (const float*)d_in[2];
    const float* q_norm_w  = (const float*)d_in[3];
    const float* k_norm_w  = (const float*)d_in[4];
    const float* w_o       = (const float*)d_in[5];
    float* out = (float*)d_out;

    char* ws = (char*)d_ws;
    // layout (144 MB):
    //   [0,16M)    hs bf16            (dead after gemm1; reused as attnb bf16)
    //   [16M,64M)  w_qkv^T bf16       (dead after gemm1; qb/kb/vbT live here after)
    //     [16M,32M) qb bf16 [T][32][128]
    //     [32M,36M) kb bf16 [T][8][128]
    //     [36M,40M) vbT bf16 [8][128][T]
    //   [64M,96M)  w_o^T bf16
    //   [96M,144M) qkv fp32
    unsigned short* hsb   = (unsigned short*)(ws);
    unsigned short* wqkvt = (unsigned short*)(ws + (size_t)(16u << 20));
    unsigned short* wot   = (unsigned short*)(ws + (size_t)(64u << 20));
    float*          qkv   = (float*)         (ws + (size_t)(96u << 20));
    unsigned short* qb    = (unsigned short*)(ws + (size_t)(16u << 20));
    unsigned short* kb    = (unsigned short*)(ws + (size_t)(32u << 20));
    unsigned short* vbT   = (unsigned short*)(ws + (size_t)(36u << 20));
    unsigned short* attnb = hsb;   // alias: hs-bf16 dead after gemm1

    convert_bf16_kernel<<<dim3((T_SEQ * HIDDEN / 4 + 255) / 256), 256, 0, stream>>>(
        hs, hsb, T_SEQ * HIDDEN / 4);
    transpose_bf16_kernel<<<dim3(NQKV / 32, HIDDEN / 32), dim3(32, 8), 0, stream>>>(
        w_qkv, wqkvt, HIDDEN, NQKV);
    transpose_bf16_kernel<<<dim3(HIDDEN / 32, HIDDEN / 32), dim3(32, 8), 0, stream>>>(
        w_o, wot, HIDDEN, HIDDEN);
    gemm_bt_kernel<<<dim3(NQKV / 128, T_SEQ / 128), 256, 0, stream>>>(
        hsb, wqkvt, qkv, T_SEQ, NQKV, HIDDEN);
    norm_rope_kernel<<<dim3(T_SEQ * 40), 128, 0, stream>>>(
        qkv, positions, q_norm_w, k_norm_w, qb, kb);
    vtrans_kernel<<<dim3(T_SEQ / 32, HDIM / 32, NKV), dim3(32, 8), 0, stream>>>(
        qkv, vbT);
    attention_kernel<<<dim3((T_SEQ / 64) * NHEAD), 256, 0, stream>>>(
        qb, kb, vbT, attnb);
    gemm_bt_kernel<<<dim3(HIDDEN / 128, T_SEQ / 128), 256, 0, stream>>>(
        attnb, wot, out, T_SEQ, HIDDEN, HIDDEN);
}